// Round 9
// baseline (206.641 us; speedup 1.0000x reference)
//
#include <hip/hip_runtime.h>
#include <math.h>

#define B_ 64
#define S_ 129
#define F_ 768
#define N3 192            // 3*B
#define BF 49152          // B*F
#define NCHUNK 1548       // S * (F/64)
#define GMAIN 256
#define GSZ 36864         // 192*192

// ws float offsets
#define WS_NM   0
#define WS_SV   3072
#define WS_C1   6144
#define WS_C0   55296
#define WS_HGM  104448
#define WS_HGS  153600
#define WS_S1   202752
#define WS_S2   251904
#define WS_PART 337920

// out float offsets
#define OUT_LOSS 6340608
#define OUT_NM   6340609
#define OUT_NV   6343681

typedef unsigned int uint;
using short8v = __attribute__((ext_vector_type(8))) short;
using float4v = __attribute__((ext_vector_type(4))) float;

// ---------------- K1: per-(b,f) sums over S, fused S-split + LDS reduce ------------
__global__ void k_stats(const float* __restrict__ x,
                        float* __restrict__ s1, float* __restrict__ s2) {
    __shared__ float4 r1[256], r2[256];
    int b = blockIdx.x / 3, fg = blockIdx.x % 3;
    int c = threadIdx.x & 63, sp = threadIdx.x >> 6;
    int f = fg * 256 + c * 4;
    const float* p = x + (size_t)b * S_ * F_ + f;
    int s0 = sp * 32;
    int se = s0 + 32 + (sp == 3 ? 1 : 0);
    float4 a1 = {0.f,0.f,0.f,0.f}, a2 = {0.f,0.f,0.f,0.f};
#pragma unroll 4
    for (int s = s0; s < se; ++s) {
        float4 v = *(const float4*)(p + s * F_);
        a1.x += v.x; a1.y += v.y; a1.z += v.z; a1.w += v.w;
        a2.x += v.x*v.x; a2.y += v.y*v.y; a2.z += v.z*v.z; a2.w += v.w*v.w;
    }
    r1[threadIdx.x] = a1; r2[threadIdx.x] = a2;
    __syncthreads();
    if (sp == 0) {
        float4 t1 = r1[c], t2 = r2[c];
#pragma unroll
        for (int k = 1; k < 4; ++k) {
            float4 u1 = r1[k * 64 + c], u2 = r2[k * 64 + c];
            t1.x += u1.x; t1.y += u1.y; t1.z += u1.z; t1.w += u1.w;
            t2.x += u2.x; t2.y += u2.y; t2.z += u2.z; t2.w += u2.w;
        }
        *(float4*)(s1 + b * F_ + f) = t1;
        *(float4*)(s2 + b * F_ + f) = t2;
    }
}

// ---------------- K2: per-domain stats (branchless) ----------------
__global__ void k_dom(const float* __restrict__ s1, const float* __restrict__ s2,
                      const int* __restrict__ domain,
                      const float* __restrict__ mean_buf, const float* __restrict__ var_buf,
                      float* __restrict__ nm_tab, float* __restrict__ sv_tab,
                      float* __restrict__ out_nm, float* __restrict__ out_nv) {
    int idx = blockIdx.x * 256 + threadIdx.x;    // 0..3071 = f*4+d
    if (idx >= F_ * 4) return;
    int f = idx >> 2, d = idx & 3;
    float a1 = 0.f, a2 = 0.f, cntf = 0.f;
#pragma unroll 8
    for (int b = 0; b < B_; ++b) {
        float v1 = s1[b * F_ + f];
        float v2 = s2[b * F_ + f];
        bool mk = (domain[b] == d);
        a1 += mk ? v1 : 0.0f;
        a2 += mk ? v2 : 0.0f;
        cntf += mk ? 1.0f : 0.0f;
    }
    float nm, nv;
    if (cntf > 0.f) {
        float n = cntf * (float)S_;
        float mu = a1 / n;
        float var = (a2 - n * mu * mu) / fmaxf(n - 1.0f, 1.0f);
        nm = 0.9f * mean_buf[d * F_ + f] + 0.1f * mu;
        nv = 0.9f * var_buf[d * F_ + f] + 0.1f * var;
    } else {
        nm = mean_buf[d * F_ + f];
        nv = var_buf[d * F_ + f];
    }
    out_nm[d * F_ + f] = nm;
    out_nv[d * F_ + f] = nv;
    nm_tab[d * F_ + f] = nm;
    sv_tab[d * F_ + f] = sqrtf(nv + 1e-6f);
}

// ---------------- K2b: per-(b,f) mix/hg coefficients (+ zero loss) -----------------
__global__ void k_coef(const float* __restrict__ s1, const float* __restrict__ s2,
                       const float* __restrict__ lmda,
                       const int* __restrict__ domain, const int* __restrict__ d_rand,
                       const float* __restrict__ nm_tab, const float* __restrict__ sv_tab,
                       float* __restrict__ c1, float* __restrict__ c0,
                       float* __restrict__ hgm, float* __restrict__ hgs,
                       float* __restrict__ out_loss) {
    int t = blockIdx.x * 256 + threadIdx.x;      // 0..49151
    if (blockIdx.x == 0 && threadIdx.x == 0) out_loss[0] = 0.0f;
    int b = t / F_, f = t - b * F_;
    float mu = s1[t] * (1.0f / (float)S_);
    float v  = (s2[t] - (float)S_ * mu * mu) * (1.0f / (float)(S_ - 1));
    float r  = rsqrtf(v + 1e-6f);
    int dm = domain[b];
    int ds = (dm + d_rand[b]) & 3;               // D == 4
    float sv = sv_tab[ds * F_ + f];
    float nm = nm_tab[ds * F_ + f];
    float lam = lmda[b];
    float rs = r * sv;
    c1[t] = lam + (1.0f - lam) * rs;
    c0[t] = (1.0f - lam) * (nm - mu * rs);
    hgm[t] = nm_tab[dm * F_ + f];
    hgs[t] = sv_tab[dm * F_ + f];
}

// ---------------- bf16 helpers ----------------
__device__ __forceinline__ uint pack2(float a, float b) {
    uint ua = __float_as_uint(a);
    uint ub = __float_as_uint(b);
    uint ha = (ua + 0x7FFFu + ((ua >> 16) & 1u)) >> 16;
    uint hb = (ub + 0x7FFFu + ((ub >> 16) & 1u)) & 0xFFFF0000u;
    return hb | ha;
}

__device__ __forceinline__ void bf16_store8(char* lds, int row, int g,
                                            float4 v0, float4 v1) {
    uint4 H;
    H.x = pack2(v0.x, v0.y);
    H.y = pack2(v0.z, v0.w);
    H.z = pack2(v1.x, v1.y);
    H.w = pack2(v1.z, v1.w);
    *(uint4*)(lds + row * 128 + ((g ^ (row & 7)) << 4)) = H;
}

__device__ __forceinline__ float4 fma4(float4 a, float4 x, float4 b) {
    float4 r;
    r.x = fmaf(a.x, x.x, b.x); r.y = fmaf(a.y, x.y, b.y);
    r.z = fmaf(a.z, x.z, b.z); r.w = fmaf(a.w, x.w, b.w);
    return r;
}

// ---------------- K3: fused x_mix/hg generation + MFMA Gram partials ----------------
// 256 blocks x 512 threads. 2-deep LDS dbuf, single barrier per chunk, and
// depth-2 register prefetch on the HBM streams (x, hgn): two chunks of loads in
// flight (16 KB/CU) to cover the ~900-cyc HBM latency at full BW. Coef streams
// (L2-resident) stay depth-1.
__device__ __forceinline__ void chunk_body(
    int q, char* buf,
    float4& X0, float4& X1, float4& N0, float4& N1, size_t& goff,
    float4& C1a, float4& C1b, float4& C0a, float4& C0b,
    float4& HMa, float4& HMb, float4& HSa, float4& HSb,
    const float* __restrict__ x, const float* __restrict__ hgn,
    const float* __restrict__ c1, const float* __restrict__ c0,
    const float* __restrict__ hgm, const float* __restrict__ hgs,
    float* __restrict__ xmix,
    int b, int g, int wr, int wc, int m, int qd,
    float4v (&acc)[6][3])
{
    float4 M0 = fma4(C1a, X0, C0a);
    float4 M1 = fma4(C1b, X1, C0b);
    ((float4*)(xmix + goff))[0] = M0;
    ((float4*)(xmix + goff))[1] = M1;
    float4 H0 = fma4(HSa, N0, HMa);
    float4 H1 = fma4(HSb, N1, HMb);

    bf16_store8(buf, b, g, X0, X1);
    bf16_store8(buf, 64 + b, g, M0, M1);
    bf16_store8(buf, 128 + b, g, H0, H1);
    __syncthreads();

    int q1 = q + GMAIN;
    if (q1 < NCHUNK) {                           // coef prefetch, depth-1 (L2)
        int s = q1 / 12, f0 = (q1 - s * 12) * 64;
        int cb = b * F_ + f0 + (g << 3);
        C1a = ((const float4*)(c1 + cb))[0]; C1b = ((const float4*)(c1 + cb))[1];
        C0a = ((const float4*)(c0 + cb))[0]; C0b = ((const float4*)(c0 + cb))[1];
        HMa = ((const float4*)(hgm + cb))[0]; HMb = ((const float4*)(hgm + cb))[1];
        HSa = ((const float4*)(hgs + cb))[0]; HSb = ((const float4*)(hgs + cb))[1];
    }
    int q2 = q + 2 * GMAIN;
    if (q2 < NCHUNK) {                           // HBM prefetch, depth-2
        int s = q2 / 12, f0 = (q2 - s * 12) * 64;
        goff = ((size_t)b * S_ + s) * F_ + f0 + (g << 3);
        X0 = ((const float4*)(x + goff))[0];
        X1 = ((const float4*)(x + goff))[1];
        N0 = ((const float4*)(hgn + goff))[0];
        N1 = ((const float4*)(hgn + goff))[1];
    }

#pragma unroll
    for (int t = 0; t < 2; ++t) {
        short8v A[6];
#pragma unroll
        for (int i = 0; i < 6; ++i) {
            int row = wr + i * 16 + m;
            int go = (((t << 2) + qd) ^ (row & 7)) << 4;
            A[i] = *(const short8v*)(buf + row * 128 + go);
        }
#pragma unroll
        for (int j = 0; j < 3; ++j) {
            int row = wc + j * 16 + m;
            int go = (((t << 2) + qd) ^ (row & 7)) << 4;
            short8v Bv = *(const short8v*)(buf + row * 128 + go);
#pragma unroll
            for (int i = 0; i < 6; ++i)
                acc[i][j] = __builtin_amdgcn_mfma_f32_16x16x32_bf16(A[i], Bv, acc[i][j], 0, 0, 0);
        }
    }
}

template <bool EXCL>
__global__ __launch_bounds__(512, 2)
void k_main(const float* __restrict__ x, const float* __restrict__ hgn,
            const float* __restrict__ c1, const float* __restrict__ c0,
            const float* __restrict__ hgm, const float* __restrict__ hgs,
            float* __restrict__ xmix, float* part, float* diag, int npart) {
    __shared__ __align__(16) char LDS[49152];    // 2 x (192 rows x 128 B)
    float4v acc[6][3];
#pragma unroll
    for (int i = 0; i < 6; ++i)
#pragma unroll
        for (int j = 0; j < 3; ++j)
            acc[i][j] = (float4v){0.f, 0.f, 0.f, 0.f};

    int tid = threadIdx.x;
    int b = tid >> 3;             // staging row 0..63
    int g = tid & 7;              // granule (8 floats)
    int w = tid >> 6;             // wave 0..7
    int wr = (w >> 2) * 96, wc = (w & 3) * 48;
    int lane = tid & 63, m = lane & 15, qd = lane >> 4;

    int q0 = blockIdx.x;
    size_t goA, goB;
    float4 XA0, XA1, NA0, NA1, XB0, XB1, NB0, NB1;
    float4 C1a, C1b, C0a, C0b, HMa, HMb, HSa, HSb;
    {
        int s = q0 / 12, f0 = (q0 - s * 12) * 64;
        goA = ((size_t)b * S_ + s) * F_ + f0 + (g << 3);
        int cb = b * F_ + f0 + (g << 3);
        XA0 = ((const float4*)(x + goA))[0];
        XA1 = ((const float4*)(x + goA))[1];
        NA0 = ((const float4*)(hgn + goA))[0];
        NA1 = ((const float4*)(hgn + goA))[1];
        C1a = ((const float4*)(c1 + cb))[0]; C1b = ((const float4*)(c1 + cb))[1];
        C0a = ((const float4*)(c0 + cb))[0]; C0b = ((const float4*)(c0 + cb))[1];
        HMa = ((const float4*)(hgm + cb))[0]; HMb = ((const float4*)(hgm + cb))[1];
        HSa = ((const float4*)(hgs + cb))[0]; HSb = ((const float4*)(hgs + cb))[1];
    }
    {
        int q1 = q0 + GMAIN;                     // always < NCHUNK (q0<256, NCHUNK=1548)
        int s = q1 / 12, f0 = (q1 - s * 12) * 64;
        goB = ((size_t)b * S_ + s) * F_ + f0 + (g << 3);
        XB0 = ((const float4*)(x + goB))[0];
        XB1 = ((const float4*)(x + goB))[1];
        NB0 = ((const float4*)(hgn + goB))[0];
        NB1 = ((const float4*)(hgn + goB))[1];
    }

    int par = 0;
    for (int q = q0; q < NCHUNK; q += GMAIN, par ^= 1) {
        if (par == 0)
            chunk_body(q, LDS, XA0, XA1, NA0, NA1, goA,
                       C1a, C1b, C0a, C0b, HMa, HMb, HSa, HSb,
                       x, hgn, c1, c0, hgm, hgs, xmix, b, g, wr, wc, m, qd, acc);
        else
            chunk_body(q, LDS + 24576, XB0, XB1, NB0, NB1, goB,
                       C1a, C1b, C0a, C0b, HMa, HMb, HSa, HSb,
                       x, hgn, c1, c0, hgm, hgs, xmix, b, g, wr, wc, m, qd, acc);
    }

    int slice = blockIdx.x % npart;
    float* dst  = part + (size_t)slice * GSZ;
    float* dstd = diag + (size_t)slice * N3;
#pragma unroll
    for (int i = 0; i < 6; ++i)
#pragma unroll
        for (int j = 0; j < 3; ++j) {
            int col = wc + j * 16 + m;
#pragma unroll
            for (int r = 0; r < 4; ++r) {
                int row = wr + i * 16 + qd * 4 + r;
                int o = row * N3 + col;
                float v = acc[i][j][r];
                if (EXCL) {
                    dst[o] = v;
                    if (row == col) dstd[row] = v;
                } else {
                    atomicAdd(dst + o, v);
                    if (row == col) atomicAdd(dstd + row, v);
                }
            }
        }
}

// ---------------- K4: fused gram-row reduction + triplet hard loss -----------------
// 192 blocks; block i sums gram row i over slices + the compact diag vectors.
__global__ void k_redloss(const float* __restrict__ part, const float* __restrict__ diag,
                          const int* __restrict__ labels, float* __restrict__ out_loss,
                          int npart) {
    __shared__ float sqs[N3];
    __shared__ float apw[4], anw[4];
    int i = blockIdx.x, j = threadIdx.x;         // 256 threads
    float rowv = 0.f, dv = 0.f;
    if (j < N3) {
        const float* pr = part + (size_t)i * N3 + j;
        const float* pd = diag + j;
        int p = 0;
        for (; p + 4 <= npart; p += 4) {
            rowv += pr[(size_t)(p + 0) * GSZ] + pr[(size_t)(p + 1) * GSZ]
                  + pr[(size_t)(p + 2) * GSZ] + pr[(size_t)(p + 3) * GSZ];
            dv   += pd[(p + 0) * N3] + pd[(p + 1) * N3]
                  + pd[(p + 2) * N3] + pd[(p + 3) * N3];
        }
        for (; p < npart; ++p) {
            rowv += pr[(size_t)p * GSZ];
            dv   += pd[p * N3];
        }
        sqs[j] = dv;
    }
    __syncthreads();
    float si = sqs[i];
    float ap = -1e30f, an = 1e30f;
    if (j < N3) {
        int li = (i < 128) ? labels[i & 63] : -1;
        int lj = (j < 128) ? labels[j & 63] : -1;
        float d2 = si + sqs[j] - 2.0f * rowv;
        float dist = sqrtf(fmaxf(d2, 1e-12f));
        bool pos = (li == lj);
        ap = pos ? dist : -1e30f;
        an = pos ? 1e30f : dist;
    }
#pragma unroll
    for (int off = 32; off; off >>= 1) {
        ap = fmaxf(ap, __shfl_xor(ap, off));
        an = fminf(an, __shfl_xor(an, off));
    }
    int wv = j >> 6;
    if ((j & 63) == 0) { apw[wv] = ap; anw[wv] = an; }
    __syncthreads();
    if (j == 0) {
        float a = fmaxf(fmaxf(apw[0], apw[1]), fmaxf(apw[2], apw[3]));
        float n = fminf(fminf(anw[0], anw[1]), fminf(anw[2], anw[3]));
        float xv = a - n;
        float sp = fmaxf(xv, 0.0f) + log1pf(expf(-fabsf(xv)));
        atomicAdd(out_loss, sp * (1.0f / (float)N3));
    }
}

extern "C" void kernel_launch(void* const* d_in, const int* in_sizes, int n_in,
                              void* d_out, int out_size, void* d_ws, size_t ws_size,
                              hipStream_t stream) {
    const float* x        = (const float*)d_in[0];
    const float* lmda     = (const float*)d_in[1];
    const float* mean_buf = (const float*)d_in[2];
    const float* var_buf  = (const float*)d_in[3];
    const float* hgn      = (const float*)d_in[4];
    const int*   labels   = (const int*)d_in[5];
    const int*   domain   = (const int*)d_in[6];
    const int*   d_rand   = (const int*)d_in[7];
    float* out = (float*)d_out;
    float* ws  = (float*)d_ws;

    long avail = (long)(ws_size / 4) - WS_PART;
    int npart = (int)(avail / (GSZ + N3));
    if (npart < 1) npart = 1;
    if (npart > GMAIN) npart = GMAIN;
    bool excl = (npart == GMAIN);
    float* part = ws + WS_PART;
    float* diag = part + (size_t)npart * GSZ;    // contiguous after the slices

    k_stats<<<dim3(192), dim3(256), 0, stream>>>(x, ws + WS_S1, ws + WS_S2);
    k_dom<<<dim3(12), dim3(256), 0, stream>>>(ws + WS_S1, ws + WS_S2, domain,
                                              mean_buf, var_buf,
                                              ws + WS_NM, ws + WS_SV,
                                              out + OUT_NM, out + OUT_NV);
    k_coef<<<dim3(192), dim3(256), 0, stream>>>(ws + WS_S1, ws + WS_S2, lmda,
                                                domain, d_rand,
                                                ws + WS_NM, ws + WS_SV,
                                                ws + WS_C1, ws + WS_C0,
                                                ws + WS_HGM, ws + WS_HGS,
                                                out + OUT_LOSS);
    if (!excl) {
        hipMemsetAsync(part, 0, (size_t)npart * (GSZ + N3) * 4, stream);
    }
    if (excl) {
        k_main<true><<<dim3(GMAIN), dim3(512), 0, stream>>>(
            x, hgn, ws + WS_C1, ws + WS_C0, ws + WS_HGM, ws + WS_HGS,
            out, part, diag, npart);
    } else {
        k_main<false><<<dim3(GMAIN), dim3(512), 0, stream>>>(
            x, hgn, ws + WS_C1, ws + WS_C0, ws + WS_HGM, ws + WS_HGS,
            out, part, diag, npart);
    }
    k_redloss<<<dim3(N3), dim3(256), 0, stream>>>(part, diag, labels,
                                                  out + OUT_LOSS, npart);
}

// Round 10
// 156.240 us; speedup vs baseline: 1.3226x; 1.3226x over previous
//
#include <hip/hip_runtime.h>
#include <math.h>

#define B_ 64
#define S_ 129
#define F_ 768
#define N3 192            // 3*B
#define BF 49152          // B*F
#define NCHUNK 1548       // S * (F/64)
#define GMAIN 256
#define GSZ 36864         // 192*192

// ws float offsets
#define WS_NM   0
#define WS_SV   3072
#define WS_C1   6144
#define WS_C0   55296
#define WS_HGM  104448
#define WS_HGS  153600
#define WS_S1   202752
#define WS_S2   251904
#define WS_PART 337920

// out float offsets
#define OUT_LOSS 6340608
#define OUT_NM   6340609
#define OUT_NV   6343681

typedef unsigned int uint;
using short8v = __attribute__((ext_vector_type(8))) short;
using float4v = __attribute__((ext_vector_type(4))) float;

// ---------------- K1: per-(b,f) sums over S, fused S-split + LDS reduce ------------
// 192 blocks = (b, f-group of 256 floats); 4 waves split S; LDS combine.
__global__ void k_stats(const float* __restrict__ x,
                        float* __restrict__ s1, float* __restrict__ s2) {
    __shared__ float4 r1[256], r2[256];
    int b = blockIdx.x / 3, fg = blockIdx.x % 3;
    int c = threadIdx.x & 63, sp = threadIdx.x >> 6;
    int f = fg * 256 + c * 4;
    const float* p = x + (size_t)b * S_ * F_ + f;
    int s0 = sp * 32;
    int se = s0 + 32 + (sp == 3 ? 1 : 0);
    float4 a1 = {0.f,0.f,0.f,0.f}, a2 = {0.f,0.f,0.f,0.f};
#pragma unroll 4
    for (int s = s0; s < se; ++s) {
        float4 v = *(const float4*)(p + s * F_);
        a1.x += v.x; a1.y += v.y; a1.z += v.z; a1.w += v.w;
        a2.x += v.x*v.x; a2.y += v.y*v.y; a2.z += v.z*v.z; a2.w += v.w*v.w;
    }
    r1[threadIdx.x] = a1; r2[threadIdx.x] = a2;
    __syncthreads();
    if (sp == 0) {
        float4 t1 = r1[c], t2 = r2[c];
#pragma unroll
        for (int k = 1; k < 4; ++k) {
            float4 u1 = r1[k * 64 + c], u2 = r2[k * 64 + c];
            t1.x += u1.x; t1.y += u1.y; t1.z += u1.z; t1.w += u1.w;
            t2.x += u2.x; t2.y += u2.y; t2.z += u2.z; t2.w += u2.w;
        }
        *(float4*)(s1 + b * F_ + f) = t1;
        *(float4*)(s2 + b * F_ + f) = t2;
    }
}

// ---------------- K2: per-domain stats (branchless, combined s1/s2) ----------------
__global__ void k_dom(const float* __restrict__ s1, const float* __restrict__ s2,
                      const int* __restrict__ domain,
                      const float* __restrict__ mean_buf, const float* __restrict__ var_buf,
                      float* __restrict__ nm_tab, float* __restrict__ sv_tab,
                      float* __restrict__ out_nm, float* __restrict__ out_nv) {
    int idx = blockIdx.x * 256 + threadIdx.x;    // 0..3071 = f*4+d
    if (idx >= F_ * 4) return;
    int f = idx >> 2, d = idx & 3;
    float a1 = 0.f, a2 = 0.f, cntf = 0.f;
#pragma unroll 8
    for (int b = 0; b < B_; ++b) {
        float v1 = s1[b * F_ + f];
        float v2 = s2[b * F_ + f];
        bool mk = (domain[b] == d);
        a1 += mk ? v1 : 0.0f;
        a2 += mk ? v2 : 0.0f;
        cntf += mk ? 1.0f : 0.0f;
    }
    float nm, nv;
    if (cntf > 0.f) {
        float n = cntf * (float)S_;
        float mu = a1 / n;
        float var = (a2 - n * mu * mu) / fmaxf(n - 1.0f, 1.0f);
        nm = 0.9f * mean_buf[d * F_ + f] + 0.1f * mu;
        nv = 0.9f * var_buf[d * F_ + f] + 0.1f * var;
    } else {
        nm = mean_buf[d * F_ + f];
        nv = var_buf[d * F_ + f];
    }
    out_nm[d * F_ + f] = nm;
    out_nv[d * F_ + f] = nv;
    nm_tab[d * F_ + f] = nm;
    sv_tab[d * F_ + f] = sqrtf(nv + 1e-6f);
}

// ---------------- K2b: per-(b,f) mix/hg coefficients (+ zero loss) -----------------
__global__ void k_coef(const float* __restrict__ s1, const float* __restrict__ s2,
                       const float* __restrict__ lmda,
                       const int* __restrict__ domain, const int* __restrict__ d_rand,
                       const float* __restrict__ nm_tab, const float* __restrict__ sv_tab,
                       float* __restrict__ c1, float* __restrict__ c0,
                       float* __restrict__ hgm, float* __restrict__ hgs,
                       float* __restrict__ out_loss) {
    int t = blockIdx.x * 256 + threadIdx.x;      // 0..49151
    if (blockIdx.x == 0 && threadIdx.x == 0) out_loss[0] = 0.0f;
    int b = t / F_, f = t - b * F_;
    float mu = s1[t] * (1.0f / (float)S_);
    float v  = (s2[t] - (float)S_ * mu * mu) * (1.0f / (float)(S_ - 1));
    float r  = rsqrtf(v + 1e-6f);
    int dm = domain[b];
    int ds = (dm + d_rand[b]) & 3;               // D == 4
    float sv = sv_tab[ds * F_ + f];
    float nm = nm_tab[ds * F_ + f];
    float lam = lmda[b];
    float rs = r * sv;
    c1[t] = lam + (1.0f - lam) * rs;
    c0[t] = (1.0f - lam) * (nm - mu * rs);
    hgm[t] = nm_tab[dm * F_ + f];
    hgs[t] = sv_tab[dm * F_ + f];
}

// ---------------- bf16 helpers ----------------
__device__ __forceinline__ uint pack2(float a, float b) {
    uint ua = __float_as_uint(a);
    uint ub = __float_as_uint(b);
    uint ha = (ua + 0x7FFFu + ((ua >> 16) & 1u)) >> 16;
    uint hb = (ub + 0x7FFFu + ((ub >> 16) & 1u)) & 0xFFFF0000u;
    return hb | ha;
}

__device__ __forceinline__ void bf16_store8(char* lds, int row, int g,
                                            float4 v0, float4 v1) {
    uint4 H;
    H.x = pack2(v0.x, v0.y);
    H.y = pack2(v0.z, v0.w);
    H.z = pack2(v1.x, v1.y);
    H.w = pack2(v1.z, v1.w);
    *(uint4*)(lds + row * 128 + ((g ^ (row & 7)) << 4)) = H;
}

__device__ __forceinline__ float4 fma4(float4 a, float4 x, float4 b) {
    float4 r;
    r.x = fmaf(a.x, x.x, b.x); r.y = fmaf(a.y, x.y, b.y);
    r.z = fmaf(a.z, x.z, b.z); r.w = fmaf(a.w, x.w, b.w);
    return r;
}

// ---------------- K3: fused x_mix/hg generation + MFMA Gram partials ----------------
// 256 blocks x 512 threads (8 waves, 1 block/CU, 2 waves/EU). Single bf16 plane.
// All six input streams register-prefetched (depth 1) across the barrier.
// NOTE (r9 post-mortem): depth-2 prefetch + two-buffer refactor spilled acc to
// scratch (WRITE_SIZE 63->180 MB, MfmaUtil ~0) — keep this flat structure.
template <bool EXCL>
__global__ __launch_bounds__(512, 2)
void k_main(const float* __restrict__ x, const float* __restrict__ hgn,
            const float* __restrict__ c1, const float* __restrict__ c0,
            const float* __restrict__ hgm, const float* __restrict__ hgs,
            float* __restrict__ xmix, float* part, int npart) {
    __shared__ __align__(16) char LDS[24576];    // 192 rows x 128 B (bf16 x 64)
    float4v acc[6][3];
#pragma unroll
    for (int i = 0; i < 6; ++i)
#pragma unroll
        for (int j = 0; j < 3; ++j)
            acc[i][j] = (float4v){0.f, 0.f, 0.f, 0.f};

    int tid = threadIdx.x;
    int b = tid >> 3;             // staging row 0..63
    int g = tid & 7;              // granule (8 floats)
    int w = tid >> 6;             // wave 0..7
    int wr = (w >> 2) * 96, wc = (w & 3) * 48;
    int lane = tid & 63, m = lane & 15, qd = lane >> 4;

    int q = blockIdx.x;
    size_t goff; int cb;
    {
        int s = q / 12, f0 = (q - s * 12) * 64;
        goff = ((size_t)b * S_ + s) * F_ + f0 + (g << 3);
        cb = b * F_ + f0 + (g << 3);
    }
    float4 X0 = ((const float4*)(x + goff))[0];
    float4 X1 = ((const float4*)(x + goff))[1];
    float4 N0 = ((const float4*)(hgn + goff))[0];
    float4 N1 = ((const float4*)(hgn + goff))[1];
    float4 C1a = ((const float4*)(c1 + cb))[0], C1b = ((const float4*)(c1 + cb))[1];
    float4 C0a = ((const float4*)(c0 + cb))[0], C0b = ((const float4*)(c0 + cb))[1];
    float4 HMa = ((const float4*)(hgm + cb))[0], HMb = ((const float4*)(hgm + cb))[1];
    float4 HSa = ((const float4*)(hgs + cb))[0], HSb = ((const float4*)(hgs + cb))[1];

    for (; q < NCHUNK; q += GMAIN) {
        float4 M0 = fma4(C1a, X0, C0a);
        float4 M1 = fma4(C1b, X1, C0b);
        ((float4*)(xmix + goff))[0] = M0;
        ((float4*)(xmix + goff))[1] = M1;
        float4 H0 = fma4(HSa, N0, HMa);
        float4 H1 = fma4(HSb, N1, HMb);

        bf16_store8(LDS, b, g, X0, X1);
        bf16_store8(LDS, 64 + b, g, M0, M1);
        bf16_store8(LDS, 128 + b, g, H0, H1);
        __syncthreads();

        // prefetch next chunk (all six streams) while the MFMA section runs
        int qn = q + GMAIN;
        if (qn < NCHUNK) {
            int s = qn / 12, f0 = (qn - s * 12) * 64;
            goff = ((size_t)b * S_ + s) * F_ + f0 + (g << 3);
            cb = b * F_ + f0 + (g << 3);
            X0 = ((const float4*)(x + goff))[0];
            X1 = ((const float4*)(x + goff))[1];
            N0 = ((const float4*)(hgn + goff))[0];
            N1 = ((const float4*)(hgn + goff))[1];
            C1a = ((const float4*)(c1 + cb))[0]; C1b = ((const float4*)(c1 + cb))[1];
            C0a = ((const float4*)(c0 + cb))[0]; C0b = ((const float4*)(c0 + cb))[1];
            HMa = ((const float4*)(hgm + cb))[0]; HMb = ((const float4*)(hgm + cb))[1];
            HSa = ((const float4*)(hgs + cb))[0]; HSb = ((const float4*)(hgs + cb))[1];
        }

#pragma unroll
        for (int t = 0; t < 2; ++t) {
            short8v A[6];
#pragma unroll
            for (int i = 0; i < 6; ++i) {
                int row = wr + i * 16 + m;
                int go = (((t << 2) + qd) ^ (row & 7)) << 4;
                A[i] = *(const short8v*)(LDS + row * 128 + go);
            }
#pragma unroll
            for (int j = 0; j < 3; ++j) {
                int row = wc + j * 16 + m;
                int go = (((t << 2) + qd) ^ (row & 7)) << 4;
                short8v Bv = *(const short8v*)(LDS + row * 128 + go);
#pragma unroll
                for (int i = 0; i < 6; ++i)
                    acc[i][j] = __builtin_amdgcn_mfma_f32_16x16x32_bf16(A[i], Bv, acc[i][j], 0, 0, 0);
            }
        }
        __syncthreads();
    }

    float* dst = part + (size_t)(blockIdx.x % npart) * GSZ;
#pragma unroll
    for (int i = 0; i < 6; ++i)
#pragma unroll
        for (int j = 0; j < 3; ++j) {
            int base = (wr + i * 16 + qd * 4) * N3 + wc + j * 16 + m;
#pragma unroll
            for (int r = 0; r < 4; ++r) {
                int o = base + r * N3;
                if (EXCL) dst[o] = acc[i][j][r];
                else atomicAdd(dst + o, acc[i][j][r]);
            }
        }
}

// ---------------- K3b: reduce partial Grams (direct write, no atomics) -------------
__global__ void k_red(const float* __restrict__ part, float* __restrict__ gram, int npart) {
    int j = blockIdx.x * 256 + threadIdx.x;      // 0..36863
    float s = 0.0f;
#pragma unroll 8
    for (int p = 0; p < npart; ++p) s += part[(size_t)p * GSZ + j];
    gram[j] = s;
}

// ---------------- K4: triplet hard loss (one block per row) ----------------
__global__ void k_loss(const float* __restrict__ gram, const int* __restrict__ labels,
                       float* __restrict__ out_loss) {
    __shared__ float sq[N3];
    __shared__ int ln[N3];
    int i = blockIdx.x, lane = threadIdx.x;      // 64 lanes
    for (int k = lane; k < N3; k += 64) {
        sq[k] = gram[k * (N3 + 1)];
        ln[k] = (k < 128) ? labels[k & 63] : -1;
    }
    __syncthreads();
    int li = ln[i];
    float si = sq[i];
    float ap = -1e30f, an = 1e30f;
    for (int j = lane; j < N3; j += 64) {
        float d2 = si + sq[j] - 2.0f * gram[i * N3 + j];
        float dist = sqrtf(fmaxf(d2, 1e-12f));
        bool pos = (li == ln[j]);
        ap = pos ? fmaxf(ap, dist) : ap;
        an = pos ? an : fminf(an, dist);
    }
#pragma unroll
    for (int off = 32; off; off >>= 1) {
        ap = fmaxf(ap, __shfl_xor(ap, off));
        an = fminf(an, __shfl_xor(an, off));
    }
    if (lane == 0) {
        float xv = ap - an;
        float sp = fmaxf(xv, 0.0f) + log1pf(expf(-fabsf(xv)));
        atomicAdd(out_loss, sp * (1.0f / (float)N3));
    }
}

extern "C" void kernel_launch(void* const* d_in, const int* in_sizes, int n_in,
                              void* d_out, int out_size, void* d_ws, size_t ws_size,
                              hipStream_t stream) {
    const float* x        = (const float*)d_in[0];
    const float* lmda     = (const float*)d_in[1];
    const float* mean_buf = (const float*)d_in[2];
    const float* var_buf  = (const float*)d_in[3];
    const float* hgn      = (const float*)d_in[4];
    const int*   labels   = (const int*)d_in[5];
    const int*   domain   = (const int*)d_in[6];
    const int*   d_rand   = (const int*)d_in[7];
    float* out = (float*)d_out;
    float* ws  = (float*)d_ws;

    long avail = (long)(ws_size / 4) - WS_PART;
    int npart = (int)(avail / GSZ) - 1;          // reserve one slice for gram
    if (npart < 1) npart = 1;
    if (npart > GMAIN) npart = GMAIN;
    bool excl = (npart == GMAIN);
    float* part = ws + WS_PART;
    float* gram = ws + WS_PART + (size_t)npart * GSZ;   // after the slices

    k_stats<<<dim3(192), dim3(256), 0, stream>>>(x, ws + WS_S1, ws + WS_S2);
    k_dom<<<dim3(12), dim3(256), 0, stream>>>(ws + WS_S1, ws + WS_S2, domain,
                                              mean_buf, var_buf,
                                              ws + WS_NM, ws + WS_SV,
                                              out + OUT_NM, out + OUT_NV);
    k_coef<<<dim3(192), dim3(256), 0, stream>>>(ws + WS_S1, ws + WS_S2, lmda,
                                                domain, d_rand,
                                                ws + WS_NM, ws + WS_SV,
                                                ws + WS_C1, ws + WS_C0,
                                                ws + WS_HGM, ws + WS_HGS,
                                                out + OUT_LOSS);
    if (!excl) {
        hipMemsetAsync(part, 0, (size_t)npart * GSZ * 4, stream);
    }
    if (excl) {
        k_main<true><<<dim3(GMAIN), dim3(512), 0, stream>>>(
            x, hgn, ws + WS_C1, ws + WS_C0, ws + WS_HGM, ws + WS_HGS,
            out, part, npart);
    } else {
        k_main<false><<<dim3(GMAIN), dim3(512), 0, stream>>>(
            x, hgn, ws + WS_C1, ws + WS_C0, ws + WS_HGM, ws + WS_HGS,
            out, part, npart);
    }
    k_red<<<dim3(144), dim3(256), 0, stream>>>(part, gram, npart);
    k_loss<<<dim3(N3), dim3(64), 0, stream>>>(gram, labels, out + OUT_LOSS);
}